// Round 5
// baseline (2426.024 us; speedup 1.0000x reference)
//
#include <hip/hip_runtime.h>
#include <hip/hip_fp16.h>

#define B_   32
#define LQ_  96
#define NK_  2048
#define D_   384
#define H_   8
#define DH_  48
#define FF_  1536
#define MQ_  (B_*LQ_)   // 3072
#define SATT 8          // attention split-K chunks

typedef float  f32x4  __attribute__((ext_vector_type(4)));
typedef __bf16 bf16x8 __attribute__((ext_vector_type(8)));

__device__ __forceinline__ unsigned short f2bf(float f) {
  union { float f; unsigned u; } v; v.f = f;
  unsigned r = v.u + 0x7fffu + ((v.u >> 16) & 1u);
  return (unsigned short)(r >> 16);
}

// async global->LDS DMA, 16B per lane; LDS dest = wave-uniform base + lane*16
__device__ __forceinline__ void ld_g2l(const unsigned short* g, unsigned short* l) {
  __builtin_amdgcn_global_load_lds(
      (const __attribute__((address_space(1))) void*)g,
      (__attribute__((address_space(3))) void*)l, 16, 0, 0);
}

// ---------------- time embedding ---------------------------------------------
__global__ void time_embed_kernel(const float* __restrict__ ts,
                                  const float* __restrict__ w1, const float* __restrict__ b1,
                                  const float* __restrict__ w2, const float* __restrict__ b2,
                                  float* __restrict__ s_out) {
  int b = blockIdx.x, d = threadIdx.x;
  __shared__ float pe[384];
  __shared__ float h1[384];
  float t = ts[b];
  int dd = (d < 192) ? d : d - 192;
  float f = expf((float)dd * (-9.210340371976184f / 191.0f));
  float ang = t * f;
  pe[d] = (d < 192) ? sinf(ang) : cosf(ang);
  __syncthreads();
  float acc = b1[d];
  for (int k = 0; k < 384; ++k) acc += pe[k] * w1[k * 384 + d];
  h1[d] = fmaxf(acc, 0.f);
  __syncthreads();
  acc = b2[d];
  for (int k = 0; k < 384; ++k) acc += h1[k] * w2[k * 384 + d];
  s_out[b * 384 + d] = acc / (1.f + expf(-acc));   // silu
}

// ---------------- AdaLN modulation ------------------------------------------
__global__ void adaln_mod_kernel(const float* __restrict__ s,
                                 const float* __restrict__ aw, const float* __restrict__ ab,
                                 float* __restrict__ mod) {
  int b = blockIdx.x, l = blockIdx.y, c = threadIdx.x;
  __shared__ float ss[384];
  if (c < 384) ss[c] = s[b * 384 + c];
  __syncthreads();
  float acc = ab[l * 768 + c];
  const float* w = aw + (long)l * 384 * 768;
  for (int k = 0; k < 384; ++k) acc += ss[k] * w[k * 768 + c];
  mod[((long)l * 32 + b) * 768 + c] = acc;
}

// ---------------- RoPE packed half2 table ------------------------------------
__global__ void rope_pack_kernel(const float* __restrict__ xyz, __half2* __restrict__ cs,
                                 int total, int N, int ldn, int noff) {
  for (int i = blockIdx.x * blockDim.x + threadIdx.x; i < total;
       i += gridDim.x * blockDim.x) {
    int p = i % 192;
    int n = (i / 192) % N;
    int b = i / (192 * N);
    int a = p >> 6, j = p & 63;
    float div = __expf((float)j * (-9.210340371976184f / 64.0f));
    float ang = xyz[((long)b * N + n) * 3 + a] * div;
    float sv, cv;
    __sincosf(ang, &sv, &cv);
    cs[((long)b * ldn + noff + n) * 192 + p] = __floats2half2_rn(cv, sv);
  }
}

// ---------------- cast f32->bf16 with type_emb add at rows 2046/2047 ---------
__global__ void cast_type_kernel(const float* __restrict__ in, const float* __restrict__ temb,
                                 unsigned short* __restrict__ out, long total, int N) {
  for (long i = blockIdx.x * (long)blockDim.x + threadIdx.x; i < total;
       i += (long)gridDim.x * blockDim.x) {
    int d = (int)(i % 384);
    int n = (int)((i / 384) % N);
    float v = in[i];
    if (n == 2046) v += temb[3 * 384 + d];
    else if (n == 2047) v += temb[4 * 384 + d];
    out[i] = f2bf(v);
  }
}

// ---------------- weight transpose+cast: out[(l*LDN+noff+n)*K+k] = in[l][k][n]
__global__ void wtrans_kernel(const float* __restrict__ in, unsigned short* __restrict__ out,
                              long total, int K, int N, int LDN, int noff) {
  for (long i = blockIdx.x * (long)blockDim.x + threadIdx.x; i < total;
       i += (long)gridDim.x * blockDim.x) {
    long l = i / ((long)K * N);
    long rem = i - l * (long)K * N;
    int n = (int)(rem / K);
    int k = (int)(rem % K);
    out[(l * LDN + noff + n) * K + k] = f2bf(in[l * (long)K * N + (long)k * N + n]);
  }
}

// ---------------- AdaLN apply (layer 0 only) ---------------------------------
__global__ void modx_kernel(const float* __restrict__ x, const float* __restrict__ modl,
                            unsigned short* __restrict__ xq) {
  int i = blockIdx.x * blockDim.x + threadIdx.x;
  if (i >= MQ_ * D_) return;
  int d = i % 384;
  int b = (i / 384) / 96;
  float sc = modl[b * 768 + d];
  float sh = modl[b * 768 + 384 + d];
  xq[i] = f2bf(x[i] * (1.f + sc) + sh);
}

// ---------------- MFMA GEMM: 3-stage pipeline, raw vmcnt barriers ------------
#define EPI_RELU   1   // bf16 relu, row-major
#define EPI_F32    2   // f32, row-major
#define EPI_ROPE_Q 3   // rope * 1/sqrt(48), bf16 row-major
#define EPI_KV     4   // cols<384: rope-K head-major; cols>=384: V row-major [b][n][384]

// XT>0: 1-D grid, XCD-aware swizzle with XT col-tiles (row-tiles must be %8==0)
// PERM: A row gather for MLP heads: arow = (row>>5)*96 + tabOff + (row&31)
template <int EPI, int TM, int XT, int PERM>
__global__ __launch_bounds__(256)
void gemm_bt(const unsigned short* __restrict__ A, const unsigned short* __restrict__ Bt,
             const float* __restrict__ biasK, const float* __restrict__ biasV,
             void* __restrict__ Cout, void* __restrict__ Cout2,
             int Nt, int K, const __half2* __restrict__ cs, int tabOff, int nPerRow) {
  __shared__ __align__(16) unsigned short As[3][TM * 32];
  __shared__ __align__(16) unsigned short Bs[3][128 * 32];
  int tid = threadIdx.x, lane = tid & 63, wid = tid >> 6;
  int wm = (wid >> 1) * (TM / 2), wn = (wid & 1) * 64;
  int bx, byi;
  if (XT > 0) {
    int id = blockIdx.x;
    int xcd = id & 7, slot = id >> 3;
    bx = slot % XT;
    byi = (slot / XT) * 8 + xcd;   // same row-tile's col-tiles -> same XCD
  } else {
    bx = blockIdx.x; byi = blockIdx.y;
  }
  int bn = bx * 128;
  long bm = (long)byi * TM;
  int r0 = tid >> 2;
  int cg = ((tid & 3) + (tid >> 3)) & 3;   // swizzled source col-group for this slot
  int c0 = cg * 8;
  long ar0 = bm + r0, ar1 = bm + 64 + r0;
  if (PERM) {
    ar0 = (ar0 >> 5) * 96 + tabOff + (ar0 & 31);
    ar1 = (ar1 >> 5) * 96 + tabOff + (ar1 & 31);
  }
  const unsigned short* gA0 = A + ar0 * K + c0;
  const unsigned short* gA1 = A + ar1 * K + c0;
  const unsigned short* gB0 = Bt + (long)(bn + r0) * K + c0;
  const unsigned short* gB1 = Bt + (long)(bn + 64 + r0) * K + c0;
  f32x4 acc[TM / 32][4] = {};
  int nk = K >> 5;
  int la = lane & 15, lg8 = lane >> 4;
  auto stage = [&](int buf) {
    ld_g2l(gA0, &As[buf][tid * 8]);
    if (TM == 128) ld_g2l(gA1, &As[buf][2048 + tid * 8]);
    ld_g2l(gB0, &Bs[buf][tid * 8]);
    ld_g2l(gB1, &Bs[buf][2048 + tid * 8]);
    gA0 += 32; gA1 += 32; gB0 += 32; gB1 += 32;
  };
  // precompute swizzled LDS read offsets (relative to buffer base)
  int offA[TM / 32], offB[4];
#pragma unroll
  for (int i = 0; i < TM / 32; ++i) {
    int row = wm + i * 16 + la;
    offA[i] = row * 32 + ((lg8 - (row >> 1)) & 3) * 8;
  }
#pragma unroll
  for (int j = 0; j < 4; ++j) {
    int row = wn + j * 16 + la;
    offB[j] = row * 32 + ((lg8 - (row >> 1)) & 3) * 8;
  }
  stage(0);
  stage(1);
  for (int kc = 0; kc < nk; ++kc) {
    int cur = kc % 3;
    // wait only the OLDEST in-flight tile (per-wave NL loads); newest stays in flight
    if (kc < nk - 1) {
      if (TM == 128) asm volatile("s_waitcnt vmcnt(4) lgkmcnt(0)" ::: "memory");
      else           asm volatile("s_waitcnt vmcnt(3) lgkmcnt(0)" ::: "memory");
    } else {
      asm volatile("s_waitcnt vmcnt(0) lgkmcnt(0)" ::: "memory");
    }
    asm volatile("s_barrier" ::: "memory");
    if (kc + 2 < nk) stage((kc + 2) % 3);   // prefetch distance 2
    const unsigned short* Ab = &As[cur][0];
    const unsigned short* Bb = &Bs[cur][0];
    bf16x8 af[TM / 32], bfr[4];
#pragma unroll
    for (int i = 0; i < TM / 32; ++i) af[i] = *(const bf16x8*)&Ab[offA[i]];
#pragma unroll
    for (int j = 0; j < 4; ++j) bfr[j] = *(const bf16x8*)&Bb[offB[j]];
#pragma unroll
    for (int i = 0; i < TM / 32; ++i)
#pragma unroll
      for (int j = 0; j < 4; ++j)
        acc[i][j] = __builtin_amdgcn_mfma_f32_16x16x32_bf16(af[i], bfr[j], acc[i][j], 0, 0, 0);
  }
  int lr = lg8 * 4;
  const float SCALE = 0.14433756729740643f;  // 1/sqrt(48)
  bool isV = false;
  const float* bptr = biasK;
  if (EPI == EPI_KV) { isV = (bn >= 384); if (isV) bptr = biasV - 384; }
#pragma unroll
  for (int i = 0; i < TM / 32; ++i) {
#pragma unroll
    for (int r = 0; r < 4; ++r) {
      int row = (int)bm + wm + i * 16 + lr + r;
      int bb = 0, nn = 0; long ti = 0;
      if (EPI == EPI_ROPE_Q || EPI == EPI_KV) {
        bb = row / nPerRow;
        nn = row - bb * nPerRow;
        ti = ((long)bb * 2144 + tabOff + nn) * 192;
      }
#pragma unroll
      for (int j = 0; j < 4; ++j) {
        int col = bn + wn + j * 16 + la;
        float v = acc[i][j][r] + bptr[col];
        if (EPI == EPI_F32) {
          ((float*)Cout)[(long)row * Nt + col] = v;
        } else if (EPI == EPI_RELU) {
          ((unsigned short*)Cout)[(long)row * Nt + col] = f2bf(fmaxf(v, 0.f));
        } else if (EPI == EPI_KV && isV) {
          ((unsigned short*)Cout2)[(long)row * 384 + (col - 384)] = f2bf(v);
        } else {  // RoPE (Q or K)
          float pv = __shfl_xor(v, 1);  // pair partner col^1 lives in lane^1
          int p = ((col >> 7) << 6) + ((col & 127) >> 1);
          __half2 hv = cs[ti + p];
          float cc = __low2float(hv), ssv = __high2float(hv);
          float o = (col & 1) ? (v * cc + pv * ssv) : (v * cc - pv * ssv);
          if (EPI == EPI_ROPE_Q) {
            ((unsigned short*)Cout)[(long)row * Nt + col] = f2bf(o * SCALE);
          } else {
            int h = col / 48, d = col - h * 48;
            ((unsigned short*)Cout)[((long)((bb << 3) + h) * nPerRow + nn) * 48 + d] = f2bf(o);
          }
        }
      }
    }
  }
}

// ---------------- split-K flash attention: dbuf K/V, ONE raw barrier/tile ----
// Q pre-scaled by 1/sqrt(48). K head-major [bh][N][48]; V row-major [b][N][384].
__global__ __launch_bounds__(384)
void attn_part_kernel(const unsigned short* __restrict__ Q, const unsigned short* __restrict__ Kg,
                      const unsigned short* __restrict__ Vrm, float* __restrict__ Opart,
                      float* __restrict__ Lpart, int N, int S) {
  int h = blockIdx.x, b = blockIdx.y, s = blockIdx.z;
  int bh = b * 8 + h;
  int tid = threadIdx.x, lane = tid & 63, w = tid >> 6;
  __shared__ __align__(16) unsigned short Qs[96][64];
  __shared__ __align__(16) unsigned short Ks[2][32][72];
  __shared__ __align__(16) unsigned short Vst[2][64][40];  // [d][k]; row48=ones, 49..63=0
  __shared__ __align__(16) unsigned short Ps[6][16][40];
  const uint4 z4 = {0u, 0u, 0u, 0u};
  for (int e = tid; e < 576; e += 384) {
    int row = e / 6, g = e % 6;
    *(uint4*)&Qs[row][g * 8] = *(const uint4*)&Q[((long)b * 96 + row) * 384 + h * 48 + g * 8];
  }
  for (int e = tid; e < 192; e += 384) {
    int row = e >> 1, g = e & 1;
    *(uint4*)&Qs[row][48 + g * 8] = z4;
  }
  if (tid < 192) {                          // Ks pad cols 48..71 = 0, both buffers
    int pb = tid / 96, rr = (tid % 96) / 3, g = tid % 3;
    *(uint4*)&Ks[pb][rr][48 + g * 8] = z4;
  }
  // Vst rows 49..63 zero, both buffers (15 rows x 40 shorts = 75 uint4 each)
  if (tid < 150) {
    int pb = tid / 75, e = tid % 75;
    *(uint4*)(&Vst[pb][49][0] + e * 8) = z4;
  }
  if (tid < 80) {                           // Vst row 48: ones (cols<32), 0 pad
    int pb = tid / 40, c = tid % 40;
    Vst[pb][48][c] = (c < 32) ? (unsigned short)0x3F80 : (unsigned short)0;
  }
  __syncthreads();
  int la = lane & 15, lg = (lane >> 4) * 8;
  bf16x8 qf0 = *(const bf16x8*)&Qs[w * 16 + la][lg];
  bf16x8 qf1 = *(const bf16x8*)&Qs[w * 16 + la][32 + lg];
  f32x4 of[4] = {};   // [0..2] = O accum, [3] = lsum (via ones row)
  int ntile = N >> 5;
  int t0 = (s * ntile) / S, t1 = ((s + 1) * ntile) / S;
  // staging: tid<192 -> K rows; tid>=192 -> V rows (register transpose into LDS)
  int stt = (tid < 192) ? tid : tid - 192;
  int krow = stt / 6, kg = stt % 6;
  const uint4* gsrc = (tid < 192)
      ? (const uint4*)(Kg + ((long)bh * N + krow) * 48 + kg * 8)
      : (const uint4*)(Vrm + ((long)b * N + krow) * 384 + h * 48 + kg * 8);
  int tstep = (tid < 192) ? 192 : 1536;    // uint4 per 32-row tile
  uint4 pref = gsrc[(long)t0 * tstep];
  for (int it = t0; it < t1; ++it) {
    int p = it & 1;
    if (tid < 192) {
      *(uint4*)&Ks[p][krow][kg * 8] = pref;
    } else {
      union { uint4 q; unsigned short u[8]; } t; t.q = pref;
#pragma unroll
      for (int e = 0; e < 8; ++e) {
        int ee = (e + kg) & 7;              // bank rotation: 6-way -> ~2-way
        Vst[p][kg * 8 + ee][krow] = t.u[ee];
      }
    }
    asm volatile("s_waitcnt lgkmcnt(0)" ::: "memory");
    asm volatile("s_barrier" ::: "memory");  // single barrier per tile
    if (it + 1 < t1) pref = gsrc[(long)(it + 1) * tstep];
    f32x4 sc[2] = {};
#pragma unroll
    for (int ctile = 0; ctile < 2; ++ctile) {
      bf16x8 kf0 = *(const bf16x8*)&Ks[p][ctile * 16 + la][lg];
      bf16x8 kf1 = *(const bf16x8*)&Ks[p][ctile * 16 + la][32 + lg];
      sc[ctile] = __builtin_amdgcn_mfma_f32_16x16x32_bf16(qf0, kf0, sc[ctile], 0, 0, 0);
      sc[ctile] = __builtin_amdgcn_mfma_f32_16x16x32_bf16(qf1, kf1, sc[ctile], 0, 0, 0);
    }
    // fixed-max softmax: P = exp(s)  (Q pre-scaled; scores O(1), no overflow)
    int prow = (lane >> 4) * 4;
#pragma unroll
    for (int ctile = 0; ctile < 2; ++ctile)
#pragma unroll
      for (int r = 0; r < 4; ++r)
        Ps[w][prow + r][ctile * 16 + la] = f2bf(__expf(sc[ctile][r]));
    asm volatile("s_waitcnt lgkmcnt(0)" ::: "memory");  // wave-local C->A relayout
    bf16x8 pf = *(const bf16x8*)&Ps[w][la][lg];
#pragma unroll
    for (int dt = 0; dt < 4; ++dt) {
      bf16x8 vf = *(const bf16x8*)&Vst[p][dt * 16 + la][lg];
      of[dt] = __builtin_amdgcn_mfma_f32_16x16x32_bf16(pf, vf, of[dt], 0, 0, 0);
    }
    // no trailing barrier: next iter writes the other buffer
  }
  long base = ((long)s * 256 + bh) * 96;
#pragma unroll
  for (int r = 0; r < 4; ++r) {
    int qrow = w * 16 + (lane >> 4) * 4 + r;
    float L = __shfl(of[3][r], lane & 48);   // lsum lives at la==0 of each quad
#pragma unroll
    for (int dt = 0; dt < 3; ++dt)
      Opart[(base + qrow) * 48 + dt * 16 + la] = of[dt][r];
    if (la == 0) Lpart[base + qrow] = L;
  }
}

// ---------------- split-K combine: O = (sum Opart) / (sum L) ------------------
__global__ __launch_bounds__(384)
void attn_combine_kernel(const float* __restrict__ Opart, const float* __restrict__ Lpart,
                         unsigned short* __restrict__ O, int S) {
  int h = blockIdx.x, b = blockIdx.y;
  int bh = b * 8 + h;
  for (int e = threadIdx.x; e < 96 * 48; e += 384) {
    int q = e / 48, d = e % 48;
    float L = 0.f, acc = 0.f;
    for (int s = 0; s < S; ++s) {
      long ib = ((long)s * 256 + bh) * 96 + q;
      L += Lpart[ib];
      acc += Opart[ib * 48 + d];
    }
    O[((long)b * 96 + q) * 384 + h * 48 + d] = f2bf(acc / L);
  }
}

// ---------------- residual + LayerNorm (+ optional fused AdaLN for next layer)
__global__ __launch_bounds__(128)
void ln_res_kernel(const float* __restrict__ xin, const float* __restrict__ delta,
                   const float* __restrict__ g, const float* __restrict__ bt,
                   const float* __restrict__ modl,
                   float* __restrict__ xout, unsigned short* __restrict__ xbf,
                   unsigned short* __restrict__ xqb) {
  int row = blockIdx.x, tid = threadIdx.x;
  __shared__ float red[128];
  float v[3];
#pragma unroll
  for (int i = 0; i < 3; ++i) {
    int d = tid + i * 128;
    v[i] = xin[(long)row * 384 + d] + delta[(long)row * 384 + d];
  }
  red[tid] = v[0] + v[1] + v[2];
  __syncthreads();
  for (int t = 64; t > 0; t >>= 1) { if (tid < t) red[tid] += red[tid + t]; __syncthreads(); }
  float mean = red[0] / 384.f;
  __syncthreads();
  float q = 0.f;
#pragma unroll
  for (int i = 0; i < 3; ++i) { float d0 = v[i] - mean; q += d0 * d0; }
  red[tid] = q;
  __syncthreads();
  for (int t = 64; t > 0; t >>= 1) { if (tid < t) red[tid] += red[tid + t]; __syncthreads(); }
  float rstd = rsqrtf(red[0] / 384.f + 1e-5f);
  int bb = row / 96;
#pragma unroll
  for (int i = 0; i < 3; ++i) {
    int d = tid + i * 128;
    float o = (v[i] - mean) * rstd * g[d] + bt[d];
    xout[(long)row * 384 + d] = o;
    xbf[(long)row * 384 + d] = f2bf(o);
    if (modl) {
      float sc = modl[bb * 768 + d];
      float sh = modl[bb * 768 + 384 + d];
      xqb[(long)row * 384 + d] = f2bf(o * (1.f + sc) + sh);
    }
  }
}

// ---------------- tiny final head layer --------------------------------------
__global__ __launch_bounds__(64)
void rowgemm_bf(const unsigned short* __restrict__ A, const float* __restrict__ W,
                const float* __restrict__ bias, float* __restrict__ out,
                int Nc, int ooff) {
  int r = blockIdx.x, tid = threadIdx.x;
  __shared__ float as[384];
  for (int k = tid; k < 384; k += 64) {
    union { unsigned u; float f; } c; c.u = (unsigned)A[(long)r * 384 + k] << 16;
    as[k] = c.f;
  }
  __syncthreads();
  if (tid < Nc) {
    float acc = bias[tid];
    for (int k = 0; k < 384; ++k) acc += as[k] * W[k * Nc + tid];
    out[(long)r * 71 + ooff + tid] = acc;
  }
}

// =============================================================================
extern "C" void kernel_launch(void* const* d_in, const int* in_sizes, int n_in,
                              void* d_out, int out_size, void* d_ws, size_t ws_size,
                              hipStream_t stream) {
  const float* q_in    = (const float*)d_in[0];
  const float* k_cross = (const float*)d_in[1];
  const float* k_self  = (const float*)d_in[2];
  const float* q_xyz   = (const float*)d_in[3];
  const float* k_xyz   = (const float*)d_in[4];
  const float* tsteps  = (const float*)d_in[5];
  const float* t_w1 = (const float*)d_in[6];
  const float* t_b1 = (const float*)d_in[7];
  const float* t_w2 = (const float*)d_in[8];
  const float* t_b2 = (const float*)d_in[9];
  const float* type_emb = (const float*)d_in[10];
  const float* ada_w = (const float*)d_in[11];
  const float* ada_b = (const float*)d_in[12];
  const float* wq = (const float*)d_in[13]; const float* bq = (const float*)d_in[14];
  const float* wk = (const float*)d_in[15]; const float* bk = (const float*)d_in[16];
  const float* wv = (const float*)d_in[17]; const float* bv = (const float*)d_in[18];
  const float* wo = (const float*)d_in[19]; const float* bo = (const float*)d_in[20];
  const float* ln1g = (const float*)d_in[21]; const float* ln1b = (const float*)d_in[22];
  const float* fw1 = (const float*)d_in[23]; const float* fb1 = (const float*)d_in[24];
  const float* fw2 = (const float*)d_in[25]; const float* fb2 = (const float*)d_in[26];
  const float* ln2g = (const float*)d_in[27]; const float* ln2b = (const float*)d_in[28];
  const float* hw[9]; const float* hb[9];
  for (int i = 0; i < 9; ++i) { hw[i] = (const float*)d_in[29 + 2 * i]; hb[i] = (const float*)d_in[30 + 2 * i]; }

  char* ws = (char*)d_ws;
  size_t off = 0;
  auto alloc = [&](size_t bytes) -> void* {
    void* p = ws + off;
    off += (bytes + 255) & ~(size_t)255;
    return p;
  };
  float* s_silu = (float*)alloc((size_t)32 * 384 * 4);
  float* mod    = (float*)alloc((size_t)6 * 32 * 768 * 4);
  __half2* cs_all = (__half2*)alloc((size_t)32 * 2144 * 192 * 4);
  unsigned short* kcb  = (unsigned short*)alloc((size_t)32 * 2048 * 384 * 2);
  unsigned short* ksb  = (unsigned short*)alloc((size_t)32 * 2144 * 384 * 2);
  unsigned short* wqt  = (unsigned short*)alloc((size_t)6 * 384 * 384 * 2);
  unsigned short* wkvt = (unsigned short*)alloc((size_t)6 * 768 * 384 * 2);
  unsigned short* wot  = (unsigned short*)alloc((size_t)6 * 384 * 384 * 2);
  unsigned short* fw1t = (unsigned short*)alloc((size_t)6 * 384 * 1536 * 2);
  unsigned short* fw2t = (unsigned short*)alloc((size_t)6 * 384 * 1536 * 2);
  unsigned short* hwt  = (unsigned short*)alloc((size_t)6 * 384 * 384 * 2);
  float* x            = (float*)alloc((size_t)MQ_ * 384 * 4);
  unsigned short* xbf  = (unsigned short*)alloc((size_t)MQ_ * 384 * 2);
  unsigned short* xqb  = (unsigned short*)alloc((size_t)MQ_ * 384 * 2);
  unsigned short* qrope= (unsigned short*)alloc((size_t)MQ_ * 384 * 2);
  unsigned short* Kc   = (unsigned short*)alloc((size_t)256 * 2144 * 48 * 2);
  unsigned short* Vrm  = (unsigned short*)alloc((size_t)32 * 2144 * 384 * 2);
  unsigned short* aout = (unsigned short*)alloc((size_t)MQ_ * 384 * 2);
  float* tmp          = (float*)alloc((size_t)MQ_ * 384 * 4);
  unsigned short* ffh  = (unsigned short*)alloc((size_t)MQ_ * 1536 * 2);
  unsigned short* hh1  = (unsigned short*)alloc((size_t)1024 * 384 * 2);
  unsigned short* hh2  = (unsigned short*)alloc((size_t)1024 * 384 * 2);
  float* Opart        = (float*)alloc((size_t)SATT * 256 * 96 * 48 * 4);
  float* Lpart        = (float*)alloc((size_t)SATT * 256 * 96 * 4);
  (void)ws_size; (void)in_sizes; (void)n_in; (void)out_size;

  // ---- prep (layer-invariant) ----
  time_embed_kernel<<<32, 384, 0, stream>>>(tsteps, t_w1, t_b1, t_w2, t_b2, s_silu);
  adaln_mod_kernel<<<dim3(32, 6), 768, 0, stream>>>(s_silu, ada_w, ada_b, mod);
  rope_pack_kernel<<<4096, 256, 0, stream>>>(k_xyz, cs_all, 32 * 2048 * 192, 2048, 2144, 0);
  rope_pack_kernel<<<1024, 256, 0, stream>>>(q_xyz, cs_all, 32 * 96 * 192, 96, 2144, 2048);
  cast_type_kernel<<<4096, 256, 0, stream>>>(k_cross, type_emb, kcb, (long)32 * 2048 * 384, 2048);
  cast_type_kernel<<<4096, 256, 0, stream>>>(k_self, type_emb, ksb, (long)32 * 2144 * 384, 2144);
  wtrans_kernel<<<1024, 256, 0, stream>>>(wq, wqt, (long)6 * 384 * 384, 384, 384, 384, 0);
  wtrans_kernel<<<1024, 256, 0, stream>>>(wk, wkvt, (long)6 * 384 * 384, 384, 384, 768, 0);
  wtrans_kernel<<<1024, 256, 0, stream>>>(wv, wkvt, (long)6 * 384 * 384, 384, 384, 768, 384);
  wtrans_kernel<<<1024, 256, 0, stream>>>(wo, wot, (long)6 * 384 * 384, 384, 384, 384, 0);
  wtrans_kernel<<<2048, 256, 0, stream>>>(fw1, fw1t, (long)6 * 384 * 1536, 384, 1536, 1536, 0);
  wtrans_kernel<<<2048, 256, 0, stream>>>(fw2, fw2t, (long)6 * 1536 * 384, 1536, 384, 384, 0);
  for (int hd = 0; hd < 3; ++hd) {
    wtrans_kernel<<<256, 256, 0, stream>>>(hw[hd * 3 + 0], hwt + (long)(hd * 2) * 384 * 384,
                                           (long)384 * 384, 384, 384, 384, 0);
    wtrans_kernel<<<256, 256, 0, stream>>>(hw[hd * 3 + 1], hwt + (long)(hd * 2 + 1) * 384 * 384,
                                           (long)384 * 384, 384, 384, 384, 0);
  }
  hipMemcpyAsync(x, q_in, (size_t)MQ_ * 384 * 4, hipMemcpyDeviceToDevice, stream);
  modx_kernel<<<(MQ_ * 384 + 255) / 256, 256, 0, stream>>>(x, mod, xqb);

  // ---- 6 transformer layers ----
  for (int l = 0; l < 6; ++l) {
    int Nl = (l < 2) ? 2048 : 2144;
    const unsigned short* kvsrc = (l < 2) ? kcb : ksb;
    gemm_bt<EPI_ROPE_Q, 64, 0, 0><<<dim3(3, 48), 256, 0, stream>>>(
        xqb, wqt + (long)l * 384 * 384, bq + l * 384, nullptr, qrope, nullptr,
        384, 384, cs_all, 2048, 96);
    gemm_bt<EPI_KV, 128, 6, 0><<<dim3(6 * (32 * Nl / 128)), 256, 0, stream>>>(
        kvsrc, wkvt + (long)l * 768 * 384, bk + l * 384, bv + l * 384, Kc, Vrm,
        768, 384, cs_all, 0, Nl);
    attn_part_kernel<<<dim3(8, 32, SATT), 384, 0, stream>>>(qrope, Kc, Vrm, Opart, Lpart, Nl, SATT);
    attn_combine_kernel<<<dim3(8, 32), 384, 0, stream>>>(Opart, Lpart, aout, SATT);
    gemm_bt<EPI_F32, 64, 0, 0><<<dim3(3, 48), 256, 0, stream>>>(
        aout, wot + (long)l * 384 * 384, bo + l * 384, nullptr, tmp, nullptr,
        384, 384, nullptr, 0, 96);
    ln_res_kernel<<<MQ_, 128, 0, stream>>>(x, tmp, ln1g + l * 384, ln1b + l * 384,
                                           nullptr, x, xbf, nullptr);
    gemm_bt<EPI_RELU, 128, 0, 0><<<dim3(12, 24), 256, 0, stream>>>(
        xbf, fw1t + (long)l * 1536 * 384, fb1 + l * 1536, nullptr, ffh, nullptr,
        1536, 384, nullptr, 0, 96);
    gemm_bt<EPI_F32, 64, 0, 0><<<dim3(3, 48), 256, 0, stream>>>(
        ffh, fw2t + (long)l * 384 * 1536, fb2 + l * 384, nullptr, tmp, nullptr,
        384, 1536, nullptr, 0, 96);
    ln_res_kernel<<<MQ_, 128, 0, stream>>>(x, tmp, ln2g + l * 384, ln2b + l * 384,
                                           (l < 5) ? (mod + (long)(l + 1) * 32 * 768) : nullptr,
                                           x, xbf, xqb);
  }

  // ---- MLP heads: 2 MFMA layers (bf16) + tiny fp32 final ----
  const int ooffs[3] = {0, 31, 62};
  const int nouts[3] = {31, 31, 9};
  for (int hd = 0; hd < 3; ++hd) {
    gemm_bt<EPI_RELU, 64, 0, 1><<<dim3(3, 16), 256, 0, stream>>>(
        xbf, hwt + (long)(hd * 2) * 384 * 384, hb[hd * 3 + 0], nullptr, hh1, nullptr,
        384, 384, nullptr, hd * 32, 96);
    gemm_bt<EPI_RELU, 64, 0, 0><<<dim3(3, 16), 256, 0, stream>>>(
        hh1, hwt + (long)(hd * 2 + 1) * 384 * 384, hb[hd * 3 + 1], nullptr, hh2, nullptr,
        384, 384, nullptr, 0, 96);
    rowgemm_bf<<<1024, 64, 0, stream>>>(hh2, hw[hd * 3 + 2], hb[hd * 3 + 2], (float*)d_out,
                                        nouts[hd], ooffs[hd]);
  }
}

// Round 6
// 2120.382 us; speedup vs baseline: 1.1441x; 1.1441x over previous
//
#include <hip/hip_runtime.h>
#include <hip/hip_fp16.h>

#define B_   32
#define LQ_  96
#define NK_  2048
#define D_   384
#define H_   8
#define DH_  48
#define FF_  1536
#define MQ_  (B_*LQ_)   // 3072
#define SATT 8          // attention split-K chunks

typedef float  f32x4  __attribute__((ext_vector_type(4)));
typedef __bf16 bf16x8 __attribute__((ext_vector_type(8)));

__device__ __forceinline__ unsigned short f2bf(float f) {
  union { float f; unsigned u; } v; v.f = f;
  unsigned r = v.u + 0x7fffu + ((v.u >> 16) & 1u);
  return (unsigned short)(r >> 16);
}
__device__ __forceinline__ float bf2f(unsigned short u) {
  union { unsigned u; float f; } c; c.u = (unsigned)u << 16;
  return c.f;
}

// async global->LDS DMA, 16B per lane; LDS dest = wave-uniform base + lane*16
__device__ __forceinline__ void ld_g2l(const unsigned short* g, unsigned short* l) {
  __builtin_amdgcn_global_load_lds(
      (const __attribute__((address_space(1))) void*)g,
      (__attribute__((address_space(3))) void*)l, 16, 0, 0);
}

// RoPE on 8 packed bf16 (4 pairs) with 4 packed (cos,sin) half2s
__device__ __forceinline__ uint4 rope8(uint4 raw, uint4 tab, float scale) {
  union { uint4 q; unsigned short u[8]; } in, out; in.q = raw;
  union { uint4 q; __half2 h[4]; } t; t.q = tab;
#pragma unroll
  for (int i = 0; i < 4; ++i) {
    float lo = bf2f(in.u[2 * i]), hi = bf2f(in.u[2 * i + 1]);
    float c = __low2float(t.h[i]), s = __high2float(t.h[i]);
    out.u[2 * i]     = f2bf((lo * c - hi * s) * scale);
    out.u[2 * i + 1] = f2bf((hi * c + lo * s) * scale);
  }
  return out.q;
}

// ---------------- time embedding ---------------------------------------------
__global__ void time_embed_kernel(const float* __restrict__ ts,
                                  const float* __restrict__ w1, const float* __restrict__ b1,
                                  const float* __restrict__ w2, const float* __restrict__ b2,
                                  float* __restrict__ s_out) {
  int b = blockIdx.x, d = threadIdx.x;
  __shared__ float pe[384];
  __shared__ float h1[384];
  float t = ts[b];
  int dd = (d < 192) ? d : d - 192;
  float f = expf((float)dd * (-9.210340371976184f / 191.0f));
  float ang = t * f;
  pe[d] = (d < 192) ? sinf(ang) : cosf(ang);
  __syncthreads();
  float acc = b1[d];
  for (int k = 0; k < 384; ++k) acc += pe[k] * w1[k * 384 + d];
  h1[d] = fmaxf(acc, 0.f);
  __syncthreads();
  acc = b2[d];
  for (int k = 0; k < 384; ++k) acc += h1[k] * w2[k * 384 + d];
  s_out[b * 384 + d] = acc / (1.f + expf(-acc));   // silu
}

// ---------------- AdaLN modulation ------------------------------------------
__global__ void adaln_mod_kernel(const float* __restrict__ s,
                                 const float* __restrict__ aw, const float* __restrict__ ab,
                                 float* __restrict__ mod) {
  int b = blockIdx.x, l = blockIdx.y, c = threadIdx.x;
  __shared__ float ss[384];
  if (c < 384) ss[c] = s[b * 384 + c];
  __syncthreads();
  float acc = ab[l * 768 + c];
  const float* w = aw + (long)l * 384 * 768;
  for (int k = 0; k < 384; ++k) acc += ss[k] * w[k * 768 + c];
  mod[((long)l * 32 + b) * 768 + c] = acc;
}

// ---------------- RoPE packed half2 table ------------------------------------
__global__ void rope_pack_kernel(const float* __restrict__ xyz, __half2* __restrict__ cs,
                                 int total, int N, int ldn, int noff) {
  for (int i = blockIdx.x * blockDim.x + threadIdx.x; i < total;
       i += gridDim.x * blockDim.x) {
    int p = i % 192;
    int n = (i / 192) % N;
    int b = i / (192 * N);
    int a = p >> 6, j = p & 63;
    float div = __expf((float)j * (-9.210340371976184f / 64.0f));
    float ang = xyz[((long)b * N + n) * 3 + a] * div;
    float sv, cv;
    __sincosf(ang, &sv, &cv);
    cs[((long)b * ldn + noff + n) * 192 + p] = __floats2half2_rn(cv, sv);
  }
}

// ---------------- cast f32->bf16 with type_emb add at rows 2046/2047 ---------
__global__ void cast_type_kernel(const float* __restrict__ in, const float* __restrict__ temb,
                                 unsigned short* __restrict__ out, long total, int N) {
  for (long i = blockIdx.x * (long)blockDim.x + threadIdx.x; i < total;
       i += (long)gridDim.x * blockDim.x) {
    int d = (int)(i % 384);
    int n = (int)((i / 384) % N);
    float v = in[i];
    if (n == 2046) v += temb[3 * 384 + d];
    else if (n == 2047) v += temb[4 * 384 + d];
    out[i] = f2bf(v);
  }
}

// ---------------- weight transpose+cast: out[(l*LDN+noff+n)*K+k] = in[l][k][n]
__global__ void wtrans_kernel(const float* __restrict__ in, unsigned short* __restrict__ out,
                              long total, int K, int N, int LDN, int noff) {
  for (long i = blockIdx.x * (long)blockDim.x + threadIdx.x; i < total;
       i += (long)gridDim.x * blockDim.x) {
    long l = i / ((long)K * N);
    long rem = i - l * (long)K * N;
    int n = (int)(rem / K);
    int k = (int)(rem % K);
    out[(l * LDN + noff + n) * K + k] = f2bf(in[l * (long)K * N + (long)k * N + n]);
  }
}

// ---------------- AdaLN apply (layer 0 only) ---------------------------------
__global__ void modx_kernel(const float* __restrict__ x, const float* __restrict__ modl,
                            unsigned short* __restrict__ xq) {
  int i = blockIdx.x * blockDim.x + threadIdx.x;
  if (i >= MQ_ * D_) return;
  int d = i % 384;
  int b = (i / 384) / 96;
  float sc = modl[b * 768 + d];
  float sh = modl[b * 768 + 384 + d];
  xq[i] = f2bf(x[i] * (1.f + sc) + sh);
}

// ---------------- MFMA GEMM: BK=64, 2-stage, early-stage after barrier -------
#define EPI_BF16   0   // bf16, row-major (biasV!=null: col>=384 uses biasV)
#define EPI_RELU   1   // bf16 relu, row-major
#define EPI_F32    2   // f32, row-major

// XT>0: 1-D grid, XCD-aware swizzle with XT col-tiles (row-tiles must be %8==0)
// PERM: A row gather for MLP heads: arow = (row>>5)*96 + permOff + (row&31)
template <int EPI, int TM, int XT, int PERM>
__global__ __launch_bounds__(256)
void gemm_bt(const unsigned short* __restrict__ A, const unsigned short* __restrict__ Bt,
             const float* __restrict__ biasK, const float* __restrict__ biasV,
             void* __restrict__ Cout, int Nt, int K, int permOff) {
  __shared__ __align__(16) unsigned short As[2][TM * 64];
  __shared__ __align__(16) unsigned short Bs[2][128 * 64];
  int tid = threadIdx.x, lane = tid & 63, wid = tid >> 6;
  int wm = (wid >> 1) * (TM / 2), wn = (wid & 1) * 64;
  int bx, byi;
  if (XT > 0) {
    int id = blockIdx.x;
    int xcd = id & 7, slot = id >> 3;
    bx = slot % XT;
    byi = (slot / XT) * 8 + xcd;   // same row-tile's col-tiles -> same XCD
  } else {
    bx = blockIdx.x; byi = blockIdx.y;
  }
  int bn = bx * 128;
  long bm = (long)byi * TM;
  // staging geometry: chunk = 32 rows x 64 cols; thread -> row tid>>3, slot tid&7
  int t8 = tid >> 3;
  int cg = ((tid & 7) + t8) & 7;           // swizzled source col-group for this slot
  const unsigned short* gAc[TM / 32];
#pragma unroll
  for (int c = 0; c < TM / 32; ++c) {
    long ar = bm + c * 32 + t8;
    if (PERM) ar = (ar >> 5) * 96 + permOff + (ar & 31);
    gAc[c] = A + ar * K + cg * 8;
  }
  const unsigned short* gB = Bt + (long)(bn + t8) * K + cg * 8;
  f32x4 acc[TM / 32][4] = {};
  int nk = K >> 6;
  int la = lane & 15, lg8 = lane >> 4;
  auto stage = [&](int buf) {
    unsigned short* Ad = &As[buf][0];
    unsigned short* Bd = &Bs[buf][0];
#pragma unroll
    for (int c = 0; c < TM / 32; ++c) { ld_g2l(gAc[c], Ad + c * 2048 + tid * 8); gAc[c] += 64; }
#pragma unroll
    for (int c = 0; c < 4; ++c) ld_g2l(gB + (long)c * 32 * K, Bd + c * 2048 + tid * 8);
    gB += 64;
  };
  // swizzled LDS read offsets: data col-group g of row r lives at slot (g-r)&7
  int offA[TM / 32][2], offB[4][2];
#pragma unroll
  for (int i = 0; i < TM / 32; ++i) {
    int row = wm + i * 16 + la;
#pragma unroll
    for (int ks = 0; ks < 2; ++ks)
      offA[i][ks] = row * 64 + (((ks * 4 + lg8) - row) & 7) * 8;
  }
#pragma unroll
  for (int j = 0; j < 4; ++j) {
    int row = wn + j * 16 + la;
#pragma unroll
    for (int ks = 0; ks < 2; ++ks)
      offB[j][ks] = row * 64 + (((ks * 4 + lg8) - row) & 7) * 8;
  }
  stage(0);
  for (int kc = 0; kc < nk; ++kc) {
    int cur = kc & 1;
    asm volatile("s_waitcnt vmcnt(0) lgkmcnt(0)" ::: "memory");  // tile kc resident; prev readers done
    asm volatile("s_barrier" ::: "memory");
    if (kc + 1 < nk) stage(cur ^ 1);      // DMA next tile while computing this one
    const unsigned short* Ab = &As[cur][0];
    const unsigned short* Bb = &Bs[cur][0];
#pragma unroll
    for (int ks = 0; ks < 2; ++ks) {
      bf16x8 af[TM / 32], bfr[4];
#pragma unroll
      for (int i = 0; i < TM / 32; ++i) af[i] = *(const bf16x8*)&Ab[offA[i][ks]];
#pragma unroll
      for (int j = 0; j < 4; ++j) bfr[j] = *(const bf16x8*)&Bb[offB[j][ks]];
#pragma unroll
      for (int i = 0; i < TM / 32; ++i)
#pragma unroll
        for (int j = 0; j < 4; ++j)
          acc[i][j] = __builtin_amdgcn_mfma_f32_16x16x32_bf16(af[i], bfr[j], acc[i][j], 0, 0, 0);
    }
  }
  int lr = lg8 * 4;
  const float* bptr = biasK;
  if (biasV && bn >= 384) bptr = biasV - 384;
#pragma unroll
  for (int i = 0; i < TM / 32; ++i) {
#pragma unroll
    for (int r = 0; r < 4; ++r) {
      long row = bm + wm + i * 16 + lr + r;
#pragma unroll
      for (int j = 0; j < 4; ++j) {
        int col = bn + wn + j * 16 + la;
        float v = acc[i][j][r] + bptr[col];
        if (EPI == EPI_F32)      ((float*)Cout)[row * Nt + col] = v;
        else if (EPI == EPI_RELU) ((unsigned short*)Cout)[row * Nt + col] = f2bf(fmaxf(v, 0.f));
        else                      ((unsigned short*)Cout)[row * Nt + col] = f2bf(v);
      }
    }
  }
}

// ---------------- split-K flash attention: RoPE fused at staging --------------
// Q plain [3072,384]; KV fused [b*N+n][768] (K cols 0..383, V cols 384..767).
// RoPE applied to Q at load (with 1/sqrt(48)) and K at staging. lsum via ones-row.
__global__ __launch_bounds__(384)
void attn_part_kernel(const unsigned short* __restrict__ Q, const unsigned short* __restrict__ KV,
                      const __half2* __restrict__ cs, float* __restrict__ Opart,
                      float* __restrict__ Lpart, int N, int S) {
  int h = blockIdx.x, b = blockIdx.y, s = blockIdx.z;
  int bh = b * 8 + h;
  int tid = threadIdx.x, lane = tid & 63, w = tid >> 6;
  __shared__ __align__(16) unsigned short Qs[96][64];
  __shared__ __align__(16) unsigned short Ks[2][32][72];
  __shared__ __align__(16) unsigned short Vst[2][64][40];  // [d][k]; row48=ones, 49..63=0
  __shared__ __align__(16) unsigned short Ps[6][16][40];
  const uint4 z4 = {0u, 0u, 0u, 0u};
  const float SCALE = 0.14433756729740643f;  // 1/sqrt(48)
  for (int e = tid; e < 576; e += 384) {     // Q load + RoPE + scale
    int row = e / 6, g = e % 6;
    int col = h * 48 + g * 8;
    uint4 qraw = *(const uint4*)&Q[((long)b * 96 + row) * 384 + col];
    int pb = ((col >> 7) << 6) + ((col & 127) >> 1);
    uint4 tb = *(const uint4*)&cs[((long)b * 2144 + 2048 + row) * 192 + pb];
    *(uint4*)&Qs[row][g * 8] = rope8(qraw, tb, SCALE);
  }
  for (int e = tid; e < 192; e += 384) {
    int row = e >> 1, g = e & 1;
    *(uint4*)&Qs[row][48 + g * 8] = z4;
  }
  if (tid < 192) {                          // Ks pad cols 48..71 = 0, both buffers
    int pb = tid / 96, rr = (tid % 96) / 3, g = tid % 3;
    *(uint4*)&Ks[pb][rr][48 + g * 8] = z4;
  }
  if (tid < 150) {                          // Vst rows 49..63 zero, both buffers
    int pb = tid / 75, e = tid % 75;
    *(uint4*)(&Vst[pb][49][0] + e * 8) = z4;
  }
  if (tid < 80) {                           // Vst row 48: ones (cols<32), 0 pad
    int pb = tid / 40, c = tid % 40;
    Vst[pb][48][c] = (c < 32) ? (unsigned short)0x3F80 : (unsigned short)0;
  }
  __syncthreads();
  int la = lane & 15, lg = (lane >> 4) * 8;
  bf16x8 qf0 = *(const bf16x8*)&Qs[w * 16 + la][lg];
  bf16x8 qf1 = *(const bf16x8*)&Qs[w * 16 + la][32 + lg];
  f32x4 of[4] = {};   // [0..2] = O accum, [3] = lsum (via ones row)
  int ntile = N >> 5;
  int t0 = (s * ntile) / S, t1 = ((s + 1) * ntile) / S;
  // staging: tid<192 -> K rows (+RoPE); tid>=192 -> V rows (transpose into LDS)
  int stt = (tid < 192) ? tid : tid - 192;
  int krow = stt / 6, kg = stt % 6;
  int colK = h * 48 + kg * 8;
  int pbK = ((colK >> 7) << 6) + ((colK & 127) >> 1);
  const uint4* gD = (const uint4*)(KV + ((long)b * N + krow) * 768 +
                                   ((tid < 192) ? colK : (384 + colK)));
  const uint4* gT = (const uint4*)(cs + ((long)b * 2144 + krow) * 192 + pbK);
  uint4 pref = gD[(long)t0 * 3072];        // 32 rows * 768 shorts = 3072 uint4
  uint4 tpref = (tid < 192) ? gT[(long)t0 * 1536] : z4;   // 32 rows * 192 half2 = 1536 uint4
  for (int it = t0; it < t1; ++it) {
    int p = it & 1;
    if (tid < 192) {
      *(uint4*)&Ks[p][krow][kg * 8] = rope8(pref, tpref, 1.f);
    } else {
      union { uint4 q; unsigned short u[8]; } t; t.q = pref;
#pragma unroll
      for (int e = 0; e < 8; ++e) {
        int ee = (e + kg) & 7;              // bank rotation
        Vst[p][kg * 8 + ee][krow] = t.u[ee];
      }
    }
    asm volatile("s_waitcnt lgkmcnt(0)" ::: "memory");
    asm volatile("s_barrier" ::: "memory");  // single barrier per tile
    if (it + 1 < t1) {
      pref = gD[(long)(it + 1) * 3072];
      if (tid < 192) tpref = gT[(long)(it + 1) * 1536];
    }
    f32x4 sc[2] = {};
#pragma unroll
    for (int ctile = 0; ctile < 2; ++ctile) {
      bf16x8 kf0 = *(const bf16x8*)&Ks[p][ctile * 16 + la][lg];
      bf16x8 kf1 = *(const bf16x8*)&Ks[p][ctile * 16 + la][32 + lg];
      sc[ctile] = __builtin_amdgcn_mfma_f32_16x16x32_bf16(qf0, kf0, sc[ctile], 0, 0, 0);
      sc[ctile] = __builtin_amdgcn_mfma_f32_16x16x32_bf16(qf1, kf1, sc[ctile], 0, 0, 0);
    }
    // fixed-max softmax: P = exp(s)  (Q pre-scaled; scores O(1), no overflow)
    int prow = (lane >> 4) * 4;
#pragma unroll
    for (int ctile = 0; ctile < 2; ++ctile)
#pragma unroll
      for (int r = 0; r < 4; ++r)
        Ps[w][prow + r][ctile * 16 + la] = f2bf(__expf(sc[ctile][r]));
    asm volatile("s_waitcnt lgkmcnt(0)" ::: "memory");  // wave-local C->A relayout
    bf16x8 pf = *(const bf16x8*)&Ps[w][la][lg];
#pragma unroll
    for (int dt = 0; dt < 4; ++dt) {
      bf16x8 vf = *(const bf16x8*)&Vst[p][dt * 16 + la][lg];
      of[dt] = __builtin_amdgcn_mfma_f32_16x16x32_bf16(pf, vf, of[dt], 0, 0, 0);
    }
    // no trailing barrier: next iter writes the other buffer
  }
  long base = ((long)s * 256 + bh) * 96;
#pragma unroll
  for (int r = 0; r < 4; ++r) {
    int qrow = w * 16 + (lane >> 4) * 4 + r;
    float L = __shfl(of[3][r], lane & 48);
#pragma unroll
    for (int dt = 0; dt < 3; ++dt)
      Opart[(base + qrow) * 48 + dt * 16 + la] = of[dt][r];
    if (la == 0) Lpart[base + qrow] = L;
  }
}

// ---------------- split-K combine: O = (sum Opart) / (sum L) ------------------
__global__ __launch_bounds__(384)
void attn_combine_kernel(const float* __restrict__ Opart, const float* __restrict__ Lpart,
                         unsigned short* __restrict__ O, int S) {
  int h = blockIdx.x, b = blockIdx.y;
  int bh = b * 8 + h;
  for (int e = threadIdx.x; e < 96 * 48; e += 384) {
    int q = e / 48, d = e % 48;
    float L = 0.f, acc = 0.f;
    for (int s = 0; s < S; ++s) {
      long ib = ((long)s * 256 + bh) * 96 + q;
      L += Lpart[ib];
      acc += Opart[ib * 48 + d];
    }
    O[((long)b * 96 + q) * 384 + h * 48 + d] = f2bf(acc / L);
  }
}

// ---------------- residual + LayerNorm (+ optional fused AdaLN for next layer)
__global__ __launch_bounds__(128)
void ln_res_kernel(const float* __restrict__ xin, const float* __restrict__ delta,
                   const float* __restrict__ g, const float* __restrict__ bt,
                   const float* __restrict__ modl,
                   float* __restrict__ xout, unsigned short* __restrict__ xbf,
                   unsigned short* __restrict__ xqb) {
  int row = blockIdx.x, tid = threadIdx.x;
  __shared__ float red[128];
  float v[3];
#pragma unroll
  for (int i = 0; i < 3; ++i) {
    int d = tid + i * 128;
    v[i] = xin[(long)row * 384 + d] + delta[(long)row * 384 + d];
  }
  red[tid] = v[0] + v[1] + v[2];
  __syncthreads();
  for (int t = 64; t > 0; t >>= 1) { if (tid < t) red[tid] += red[tid + t]; __syncthreads(); }
  float mean = red[0] / 384.f;
  __syncthreads();
  float q = 0.f;
#pragma unroll
  for (int i = 0; i < 3; ++i) { float d0 = v[i] - mean; q += d0 * d0; }
  red[tid] = q;
  __syncthreads();
  for (int t = 64; t > 0; t >>= 1) { if (tid < t) red[tid] += red[tid + t]; __syncthreads(); }
  float rstd = rsqrtf(red[0] / 384.f + 1e-5f);
  int bb = row / 96;
#pragma unroll
  for (int i = 0; i < 3; ++i) {
    int d = tid + i * 128;
    float o = (v[i] - mean) * rstd * g[d] + bt[d];
    xout[(long)row * 384 + d] = o;
    xbf[(long)row * 384 + d] = f2bf(o);
    if (modl) {
      float sc = modl[bb * 768 + d];
      float sh = modl[bb * 768 + 384 + d];
      xqb[(long)row * 384 + d] = f2bf(o * (1.f + sc) + sh);
    }
  }
}

// ---------------- tiny final head layer --------------------------------------
__global__ __launch_bounds__(64)
void rowgemm_bf(const unsigned short* __restrict__ A, const float* __restrict__ W,
                const float* __restrict__ bias, float* __restrict__ out,
                int Nc, int ooff) {
  int r = blockIdx.x, tid = threadIdx.x;
  __shared__ float as[384];
  for (int k = tid; k < 384; k += 64) as[k] = bf2f(A[(long)r * 384 + k]);
  __syncthreads();
  if (tid < Nc) {
    float acc = bias[tid];
    for (int k = 0; k < 384; ++k) acc += as[k] * W[k * Nc + tid];
    out[(long)r * 71 + ooff + tid] = acc;
  }
}

// =============================================================================
extern "C" void kernel_launch(void* const* d_in, const int* in_sizes, int n_in,
                              void* d_out, int out_size, void* d_ws, size_t ws_size,
                              hipStream_t stream) {
  const float* q_in    = (const float*)d_in[0];
  const float* k_cross = (const float*)d_in[1];
  const float* k_self  = (const float*)d_in[2];
  const float* q_xyz   = (const float*)d_in[3];
  const float* k_xyz   = (const float*)d_in[4];
  const float* tsteps  = (const float*)d_in[5];
  const float* t_w1 = (const float*)d_in[6];
  const float* t_b1 = (const float*)d_in[7];
  const float* t_w2 = (const float*)d_in[8];
  const float* t_b2 = (const float*)d_in[9];
  const float* type_emb = (const float*)d_in[10];
  const float* ada_w = (const float*)d_in[11];
  const float* ada_b = (const float*)d_in[12];
  const float* wq = (const float*)d_in[13]; const float* bq = (const float*)d_in[14];
  const float* wk = (const float*)d_in[15]; const float* bk = (const float*)d_in[16];
  const float* wv = (const float*)d_in[17]; const float* bv = (const float*)d_in[18];
  const float* wo = (const float*)d_in[19]; const float* bo = (const float*)d_in[20];
  const float* ln1g = (const float*)d_in[21]; const float* ln1b = (const float*)d_in[22];
  const float* fw1 = (const float*)d_in[23]; const float* fb1 = (const float*)d_in[24];
  const float* fw2 = (const float*)d_in[25]; const float* fb2 = (const float*)d_in[26];
  const float* ln2g = (const float*)d_in[27]; const float* ln2b = (const float*)d_in[28];
  const float* hw[9]; const float* hb[9];
  for (int i = 0; i < 9; ++i) { hw[i] = (const float*)d_in[29 + 2 * i]; hb[i] = (const float*)d_in[30 + 2 * i]; }

  char* ws = (char*)d_ws;
  size_t off = 0;
  auto alloc = [&](size_t bytes) -> void* {
    void* p = ws + off;
    off += (bytes + 255) & ~(size_t)255;
    return p;
  };
  float* s_silu = (float*)alloc((size_t)32 * 384 * 4);
  float* mod    = (float*)alloc((size_t)6 * 32 * 768 * 4);
  __half2* cs_all = (__half2*)alloc((size_t)32 * 2144 * 192 * 4);
  unsigned short* kcb  = (unsigned short*)alloc((size_t)32 * 2048 * 384 * 2);
  unsigned short* ksb  = (unsigned short*)alloc((size_t)32 * 2144 * 384 * 2);
  unsigned short* wqt  = (unsigned short*)alloc((size_t)6 * 384 * 384 * 2);
  unsigned short* wkvt = (unsigned short*)alloc((size_t)6 * 768 * 384 * 2);
  unsigned short* wot  = (unsigned short*)alloc((size_t)6 * 384 * 384 * 2);
  unsigned short* fw1t = (unsigned short*)alloc((size_t)6 * 384 * 1536 * 2);
  unsigned short* fw2t = (unsigned short*)alloc((size_t)6 * 384 * 1536 * 2);
  unsigned short* hwt  = (unsigned short*)alloc((size_t)6 * 384 * 384 * 2);
  float* x            = (float*)alloc((size_t)MQ_ * 384 * 4);
  unsigned short* xbf  = (unsigned short*)alloc((size_t)MQ_ * 384 * 2);
  unsigned short* xqb  = (unsigned short*)alloc((size_t)MQ_ * 384 * 2);
  unsigned short* qb   = (unsigned short*)alloc((size_t)MQ_ * 384 * 2);
  unsigned short* KVb  = (unsigned short*)alloc((size_t)32 * 2144 * 768 * 2);
  unsigned short* aout = (unsigned short*)alloc((size_t)MQ_ * 384 * 2);
  float* tmp          = (float*)alloc((size_t)MQ_ * 384 * 4);
  unsigned short* ffh  = (unsigned short*)alloc((size_t)MQ_ * 1536 * 2);
  unsigned short* hh1  = (unsigned short*)alloc((size_t)1024 * 384 * 2);
  unsigned short* hh2  = (unsigned short*)alloc((size_t)1024 * 384 * 2);
  float* Opart        = (float*)alloc((size_t)SATT * 256 * 96 * 48 * 4);
  float* Lpart        = (float*)alloc((size_t)SATT * 256 * 96 * 4);
  (void)ws_size; (void)in_sizes; (void)n_in; (void)out_size;

  // ---- prep (layer-invariant) ----
  time_embed_kernel<<<32, 384, 0, stream>>>(tsteps, t_w1, t_b1, t_w2, t_b2, s_silu);
  adaln_mod_kernel<<<dim3(32, 6), 768, 0, stream>>>(s_silu, ada_w, ada_b, mod);
  rope_pack_kernel<<<4096, 256, 0, stream>>>(k_xyz, cs_all, 32 * 2048 * 192, 2048, 2144, 0);
  rope_pack_kernel<<<1024, 256, 0, stream>>>(q_xyz, cs_all, 32 * 96 * 192, 96, 2144, 2048);
  cast_type_kernel<<<4096, 256, 0, stream>>>(k_cross, type_emb, kcb, (long)32 * 2048 * 384, 2048);
  cast_type_kernel<<<4096, 256, 0, stream>>>(k_self, type_emb, ksb, (long)32 * 2144 * 384, 2144);
  wtrans_kernel<<<1024, 256, 0, stream>>>(wq, wqt, (long)6 * 384 * 384, 384, 384, 384, 0);
  wtrans_kernel<<<1024, 256, 0, stream>>>(wk, wkvt, (long)6 * 384 * 384, 384, 384, 768, 0);
  wtrans_kernel<<<1024, 256, 0, stream>>>(wv, wkvt, (long)6 * 384 * 384, 384, 384, 768, 384);
  wtrans_kernel<<<1024, 256, 0, stream>>>(wo, wot, (long)6 * 384 * 384, 384, 384, 384, 0);
  wtrans_kernel<<<2048, 256, 0, stream>>>(fw1, fw1t, (long)6 * 384 * 1536, 384, 1536, 1536, 0);
  wtrans_kernel<<<2048, 256, 0, stream>>>(fw2, fw2t, (long)6 * 1536 * 384, 1536, 384, 384, 0);
  for (int hd = 0; hd < 3; ++hd) {
    wtrans_kernel<<<256, 256, 0, stream>>>(hw[hd * 3 + 0], hwt + (long)(hd * 2) * 384 * 384,
                                           (long)384 * 384, 384, 384, 384, 0);
    wtrans_kernel<<<256, 256, 0, stream>>>(hw[hd * 3 + 1], hwt + (long)(hd * 2 + 1) * 384 * 384,
                                           (long)384 * 384, 384, 384, 384, 0);
  }
  hipMemcpyAsync(x, q_in, (size_t)MQ_ * 384 * 4, hipMemcpyDeviceToDevice, stream);
  modx_kernel<<<(MQ_ * 384 + 255) / 256, 256, 0, stream>>>(x, mod, xqb);

  // ---- 6 transformer layers ----
  for (int l = 0; l < 6; ++l) {
    int Nl = (l < 2) ? 2048 : 2144;
    const unsigned short* kvsrc = (l < 2) ? kcb : ksb;
    gemm_bt<EPI_BF16, 64, 0, 0><<<dim3(3, 48), 256, 0, stream>>>(
        xqb, wqt + (long)l * 384 * 384, bq + l * 384, nullptr, qb, 384, 384, 0);
    gemm_bt<EPI_BF16, 128, 6, 0><<<dim3(6 * (32 * Nl / 128)), 256, 0, stream>>>(
        kvsrc, wkvt + (long)l * 768 * 384, bk + l * 384, bv + l * 384, KVb, 768, 384, 0);
    attn_part_kernel<<<dim3(8, 32, SATT), 384, 0, stream>>>(qb, KVb, cs_all, Opart, Lpart, Nl, SATT);
    attn_combine_kernel<<<dim3(8, 32), 384, 0, stream>>>(Opart, Lpart, aout, SATT);
    gemm_bt<EPI_F32, 64, 0, 0><<<dim3(3, 48), 256, 0, stream>>>(
        aout, wot + (long)l * 384 * 384, bo + l * 384, nullptr, tmp, 384, 384, 0);
    ln_res_kernel<<<MQ_, 128, 0, stream>>>(x, tmp, ln1g + l * 384, ln1b + l * 384,
                                           nullptr, x, xbf, nullptr);
    gemm_bt<EPI_RELU, 128, 0, 0><<<dim3(12, 24), 256, 0, stream>>>(
        xbf, fw1t + (long)l * 1536 * 384, fb1 + l * 1536, nullptr, ffh, 1536, 384, 0);
    gemm_bt<EPI_F32, 64, 0, 0><<<dim3(3, 48), 256, 0, stream>>>(
        ffh, fw2t + (long)l * 384 * 1536, fb2 + l * 384, nullptr, tmp, 384, 1536, 0);
    ln_res_kernel<<<MQ_, 128, 0, stream>>>(x, tmp, ln2g + l * 384, ln2b + l * 384,
                                           (l < 5) ? (mod + (long)(l + 1) * 32 * 768) : nullptr,
                                           x, xbf, xqb);
  }

  // ---- MLP heads: 2 MFMA layers (bf16) + tiny fp32 final ----
  const int ooffs[3] = {0, 31, 62};
  const int nouts[3] = {31, 31, 9};
  for (int hd = 0; hd < 3; ++hd) {
    gemm_bt<EPI_RELU, 64, 0, 1><<<dim3(3, 16), 256, 0, stream>>>(
        xbf, hwt + (long)(hd * 2) * 384 * 384, hb[hd * 3 + 0], nullptr, hh1, 384, 384, hd * 32);
    gemm_bt<EPI_RELU, 64, 0, 0><<<dim3(3, 16), 256, 0, stream>>>(
        hh1, hwt + (long)(hd * 2 + 1) * 384 * 384, hb[hd * 3 + 1], nullptr, hh2, 384, 384, 0);
    rowgemm_bf<<<1024, 64, 0, stream>>>(hh2, hw[hd * 3 + 2], hb[hd * 3 + 2], (float*)d_out,
                                        nouts[hd], ooffs[hd]);
  }
}